// Round 7
// baseline (1002.979 us; speedup 1.0000x reference)
//
#include <hip/hip_runtime.h>

#define NFEAT 256
#define NQ    64          // NFEAT/4 float4 quads
#define CH    64          // rows per chunk (64 KB LDS stage)
#define BLK   256

typedef float f32x4_native __attribute__((ext_vector_type(4)));

__device__ __forceinline__ void nt_store4(float4* p, float4 v) {
    f32x4_native n; n.x = v.x; n.y = v.y; n.z = v.z; n.w = v.w;
    __builtin_nontemporal_store(n, reinterpret_cast<f32x4_native*>(p));
}

// ---------------------------------------------------------------------------
// Kernel 0: parallel scan of lengths -> off[B+1], bs[B+1]; zero cnt/flag.
// Runs every call (graph replays must re-zero the sync state).
// ---------------------------------------------------------------------------
__global__ __launch_bounds__(BLK) void k_setup(const int* __restrict__ lengths, int B,
                                               int* __restrict__ off, int* __restrict__ bs,
                                               int* __restrict__ cnt, int* __restrict__ flag) {
    __shared__ int L[BLK], C[BLK];
    const int t = threadIdx.x;
    int len = (t < B) ? lengths[t] : 0;
    L[t] = len;
    C[t] = (len + CH - 1) / CH;
    __syncthreads();
    for (int d = 1; d < BLK; d <<= 1) {
        int a = L[t], c = C[t], aa = 0, cc = 0;
        if (t >= d) { aa = L[t - d]; cc = C[t - d]; }
        __syncthreads();
        L[t] = a + aa; C[t] = c + cc;
        __syncthreads();
    }
    if (t == 0) { off[0] = 0; bs[0] = 0; }
    if (t < B)  { off[t + 1] = L[t]; bs[t + 1] = C[t]; cnt[t] = 0; flag[t] = 0; }
}

// ---------------------------------------------------------------------------
// Fused kernel: per chunk — load x once (stage in LDS) + partials; last block
// of each segment finalizes scale/shift; all blocks of the segment spin on a
// flag, then normalize FROM LDS (zero x re-read) and nt-store out.
// ---------------------------------------------------------------------------
__global__ __launch_bounds__(BLK) void k_main(
    const float* __restrict__ x,
    const float* __restrict__ weight, const float* __restrict__ bias,
    float* __restrict__ out,
    const int* __restrict__ off, const int* __restrict__ bs, int B,
    float* __restrict__ psum, float* __restrict__ psumsq,
    float* __restrict__ scale, float* __restrict__ shift,
    int* __restrict__ cnt, int* __restrict__ flag)
{
    const int t   = threadIdx.x;
    const int bid = blockIdx.x;

    __shared__ int soff[132], sbs[132];
    __shared__ int sseg, is_last;
    if (t <= B) { soff[t] = off[t]; sbs[t] = bs[t]; }
    __syncthreads();
    if (bid >= sbs[B]) return;                      // dead tail blocks

    if (t < B && sbs[t] <= bid && bid < sbs[t + 1]) sseg = t;
    __syncthreads();
    const int seg = sseg;
    const int r0 = soff[seg] + (bid - sbs[seg]) * CH;
    const int r1 = min(r0 + CH, soff[seg + 1]);

    const int rl = t >> 6;      // row lane 0..3
    const int q  = t & 63;      // feature quad

    __shared__ float4 stage[CH * NQ];   // 64 KB: the chunk, staged once
    __shared__ float4 red[2][4][NQ];    // 8 KB reduction buffer

    // ---- Phase A: single x read -> LDS stage + per-feature partials --------
    float4 sum = make_float4(0.f, 0.f, 0.f, 0.f);
    float4 sq  = make_float4(0.f, 0.f, 0.f, 0.f);
    const float4* x4 = reinterpret_cast<const float4*>(x);
    #pragma unroll 8
    for (int r = r0 + rl; r < r1; r += 4) {
        float4 v = x4[(size_t)r * NQ + q];
        stage[((r - r0) << 6) | q] = v;
        sum.x += v.x; sum.y += v.y; sum.z += v.z; sum.w += v.w;
        sq.x  += v.x * v.x; sq.y += v.y * v.y; sq.z += v.z * v.z; sq.w += v.w * v.w;
    }
    red[0][rl][q] = sum;
    red[1][rl][q] = sq;
    __syncthreads();
    if (rl == 0) {
        float4 a0 = red[0][0][q], a1 = red[0][1][q], a2 = red[0][2][q], a3 = red[0][3][q];
        float4 q0 = red[1][0][q], q1 = red[1][1][q], q2 = red[1][2][q], q3 = red[1][3][q];
        float4 ts, tq;
        ts.x = a0.x + a1.x + a2.x + a3.x;  ts.y = a0.y + a1.y + a2.y + a3.y;
        ts.z = a0.z + a1.z + a2.z + a3.z;  ts.w = a0.w + a1.w + a2.w + a3.w;
        tq.x = q0.x + q1.x + q2.x + q3.x;  tq.y = q0.y + q1.y + q2.y + q3.y;
        tq.z = q0.z + q1.z + q2.z + q3.z;  tq.w = q0.w + q1.w + q2.w + q3.w;
        reinterpret_cast<float4*>(psum)[(size_t)bid * NQ + q]   = ts;
        reinterpret_cast<float4*>(psumsq)[(size_t)bid * NQ + q] = tq;
    }
    __syncthreads();   // compiler drains vmcnt(0) before s_barrier -> psum stores done

    // ---- Publish: release-increment segment counter -------------------------
    if (t == 0) {
        int old = __hip_atomic_fetch_add(&cnt[seg], 1,
                                         __ATOMIC_RELEASE, __HIP_MEMORY_SCOPE_AGENT);
        is_last = (old == (sbs[seg + 1] - sbs[seg] - 1));
    }
    __syncthreads();

    // ---- Last block of the segment finalizes scale/shift --------------------
    if (is_last) {
        (void)__hip_atomic_load(&cnt[seg], __ATOMIC_ACQUIRE, __HIP_MEMORY_SCOPE_AGENT);
        float s = 0.f, qq = 0.f;
        const int b0 = sbs[seg], b1 = sbs[seg + 1];
        for (int b = b0; b < b1; ++b) {
            s  += psum[(size_t)b * NFEAT + t];
            qq += psumsq[(size_t)b * NFEAT + t];
        }
        const float cf   = (float)(soff[seg + 1] - soff[seg]);
        const float m    = s / cf;
        const float var  = fmaxf(qq / cf - m * m, 0.f);
        const float rstd = rsqrtf(var + 1e-5f);
        const float sc_  = rstd * weight[t];
        scale[(size_t)seg * NFEAT + t] = sc_;
        shift[(size_t)seg * NFEAT + t] = bias[t] - m * sc_;
        __syncthreads();   // drain scale/shift stores before flag release
        if (t == 0)
            __hip_atomic_store(&flag[seg], 1, __ATOMIC_RELEASE, __HIP_MEMORY_SCOPE_AGENT);
    }

    // ---- Wait for the segment's stats (relaxed poll; ONE acquire on exit) ---
    if (t == 0) {
        while (__hip_atomic_load(&flag[seg], __ATOMIC_RELAXED,
                                 __HIP_MEMORY_SCOPE_AGENT) == 0)
            __builtin_amdgcn_s_sleep(2);
        (void)__hip_atomic_load(&flag[seg], __ATOMIC_ACQUIRE, __HIP_MEMORY_SCOPE_AGENT);
    }
    __syncthreads();

    // ---- Phase B: normalize from LDS (zero HBM re-read), nt-store out -------
    const float4 sc = reinterpret_cast<const float4*>(scale)[(size_t)seg * NQ + q];
    const float4 sh = reinterpret_cast<const float4*>(shift)[(size_t)seg * NQ + q];
    float4* o4 = reinterpret_cast<float4*>(out);
    #pragma unroll 8
    for (int r = r0 + rl; r < r1; r += 4) {
        float4 v = stage[((r - r0) << 6) | q];
        float4 o;
        o.x = v.x * sc.x + sh.x;
        o.y = v.y * sc.y + sh.y;
        o.z = v.z * sc.z + sh.z;
        o.w = v.w * sc.w + sh.w;
        nt_store4(&o4[(size_t)r * NQ + q], o);
    }
}

extern "C" void kernel_launch(void* const* d_in, const int* in_sizes, int n_in,
                              void* d_out, int out_size, void* d_ws, size_t ws_size,
                              hipStream_t stream) {
    const float* x       = (const float*)d_in[0];
    const int*   lengths = (const int*)d_in[1];
    const float* weight  = (const float*)d_in[2];
    const float* bias    = (const float*)d_in[3];
    float*       out     = (float*)d_out;

    const int B = in_sizes[1];               // 128
    const int N = in_sizes[0] / NFEAT;       // 524288
    const int maxCh = N / CH + B;            // 8320 chunk upper bound

    // ws layout
    char* ws = (char*)d_ws;
    int*   off    = (int*)ws;                                  // B+1
    int*   bs     = off + 160;                                 // B+1
    int*   cnt    = bs + 160;                                  // B
    int*   flag   = cnt + 160;                                 // B
    float* scale  = (float*)(ws + 8192);                       // B*F
    float* shift  = scale + (size_t)B * NFEAT;                 // B*F
    float* psum   = shift + (size_t)B * NFEAT;                 // maxCh*F
    float* psumsq = psum + (size_t)maxCh * NFEAT;              // maxCh*F

    k_setup<<<1, BLK, 0, stream>>>(lengths, B, off, bs, cnt, flag);
    k_main<<<maxCh, BLK, 0, stream>>>(x, weight, bias, out, off, bs, B,
                                      psum, psumsq, scale, shift, cnt, flag);
}

// Round 8
// 405.809 us; speedup vs baseline: 2.4716x; 2.4716x over previous
//
#include <hip/hip_runtime.h>

#define NFEAT 256
#define NQ    64          // NFEAT/4 float4 quads
#define CH    256         // rows per balanced chunk
#define BLK   256

typedef float f32x4_native __attribute__((ext_vector_type(4)));

__device__ __forceinline__ void nt_store4(float4* p, float4 v) {
    f32x4_native n; n.x = v.x; n.y = v.y; n.z = v.z; n.w = v.w;
    __builtin_nontemporal_store(n, reinterpret_cast<f32x4_native*>(p));
}

// ---------------------------------------------------------------------------
// Kernel 0: parallel Hillis-Steele scan of lengths -> off[B+1], bs[B+1];
// zeroes per-segment arrival counters (graph replays need the re-zero).
// ---------------------------------------------------------------------------
__global__ __launch_bounds__(BLK) void k_setup(const int* __restrict__ lengths, int B,
                                               int* __restrict__ off, int* __restrict__ bs,
                                               int* __restrict__ cnt) {
    __shared__ int L[BLK], C[BLK];
    const int t = threadIdx.x;
    int len = (t < B) ? lengths[t] : 0;
    L[t] = len;
    C[t] = (len + CH - 1) / CH;
    __syncthreads();
    for (int d = 1; d < BLK; d <<= 1) {
        int a = L[t], c = C[t], aa = 0, cc = 0;
        if (t >= d) { aa = L[t - d]; cc = C[t - d]; }
        __syncthreads();
        L[t] = a + aa; C[t] = c + cc;
        __syncthreads();
    }
    if (t == 0) { off[0] = 0; bs[0] = 0; }
    if (t < B)  { off[t + 1] = L[t]; bs[t + 1] = C[t]; cnt[t] = 0; }
}

// Chunk c -> segment s with bs[s] <= c < bs[s+1] (parallel range test).
__device__ __forceinline__ int find_seg(const int* __restrict__ sbs, int B, int c) {
    __shared__ int sseg;
    const int t = threadIdx.x;
    if (t < B && sbs[t] <= c && c < sbs[t + 1]) sseg = t;
    __syncthreads();
    return sseg;
}

// ---------------------------------------------------------------------------
// Kernel 1: per-chunk partials; the LAST arriving block of each segment also
// reduces that segment's partials -> scale/shift. No block ever waits: the
// kernel boundary before k_norm is the only consumer-side sync.
// ---------------------------------------------------------------------------
__global__ __launch_bounds__(BLK) void k_partial(const float* __restrict__ x,
                                                 const int* __restrict__ off,
                                                 const int* __restrict__ bs,
                                                 const int* __restrict__ nblkp,
                                                 int B,
                                                 const float* __restrict__ weight,
                                                 const float* __restrict__ bias,
                                                 float* __restrict__ psum,
                                                 float* __restrict__ psumsq,
                                                 float* __restrict__ scale,
                                                 float* __restrict__ shift,
                                                 int* __restrict__ cnt) {
    const int bid = blockIdx.x;
    const int t   = threadIdx.x;

    __shared__ int soff[132], sbs[132];
    __shared__ int is_last;
    if (t <= B) { soff[t] = off[t]; sbs[t] = bs[t]; }
    __syncthreads();
    if (bid >= sbs[B]) return;

    const int seg = find_seg(sbs, B, bid);
    const int r0 = soff[seg] + (bid - sbs[seg]) * CH;
    const int r1 = min(r0 + CH, soff[seg + 1]);

    const int rl = t >> 6;   // 0..3
    const int q  = t & 63;

    float4 sum = make_float4(0.f, 0.f, 0.f, 0.f);
    float4 sq  = make_float4(0.f, 0.f, 0.f, 0.f);

    const float4* x4 = reinterpret_cast<const float4*>(x);
    int r = r0 + rl;
    #pragma unroll 4
    for (; r + 4 < r1; r += 8) {                    // 2 rows in flight / iter
        float4 v0 = x4[(size_t)r * NQ + q];
        float4 v1 = x4[(size_t)(r + 4) * NQ + q];
        sum.x += v0.x; sum.y += v0.y; sum.z += v0.z; sum.w += v0.w;
        sq.x  += v0.x * v0.x; sq.y += v0.y * v0.y; sq.z += v0.z * v0.z; sq.w += v0.w * v0.w;
        sum.x += v1.x; sum.y += v1.y; sum.z += v1.z; sum.w += v1.w;
        sq.x  += v1.x * v1.x; sq.y += v1.y * v1.y; sq.z += v1.z * v1.z; sq.w += v1.w * v1.w;
    }
    if (r < r1) {
        float4 v = x4[(size_t)r * NQ + q];
        sum.x += v.x; sum.y += v.y; sum.z += v.z; sum.w += v.w;
        sq.x  += v.x * v.x; sq.y += v.y * v.y; sq.z += v.z * v.z; sq.w += v.w * v.w;
    }

    __shared__ float4 lsum[4][NQ];
    __shared__ float4 lsq[4][NQ];
    lsum[rl][q] = sum;
    lsq[rl][q]  = sq;
    __syncthreads();

    if (rl == 0) {
        float4 a0 = lsum[0][q], a1 = lsum[1][q], a2 = lsum[2][q], a3 = lsum[3][q];
        float4 q0 = lsq[0][q],  q1 = lsq[1][q],  q2 = lsq[2][q],  q3 = lsq[3][q];
        float4 ts, tq;
        ts.x = a0.x + a1.x + a2.x + a3.x;  ts.y = a0.y + a1.y + a2.y + a3.y;
        ts.z = a0.z + a1.z + a2.z + a3.z;  ts.w = a0.w + a1.w + a2.w + a3.w;
        tq.x = q0.x + q1.x + q2.x + q3.x;  tq.y = q0.y + q1.y + q2.y + q3.y;
        tq.z = q0.z + q1.z + q2.z + q3.z;  tq.w = q0.w + q1.w + q2.w + q3.w;
        // nt: partials are read once by one block — keep them out of L3's x tail
        nt_store4(&reinterpret_cast<float4*>(psum)[(size_t)bid * NQ + q],   ts);
        nt_store4(&reinterpret_cast<float4*>(psumsq)[(size_t)bid * NQ + q], tq);
    }
    __syncthreads();   // all stores issued before the arrival increment

    if (t == 0) {
        int old = __hip_atomic_fetch_add(&cnt[seg], 1,
                                         __ATOMIC_RELEASE, __HIP_MEMORY_SCOPE_AGENT);
        is_last = (old == (sbs[seg + 1] - sbs[seg] - 1));
    }
    __syncthreads();

    if (is_last) {   // only the final arriver reduces; nobody waits on it
        (void)__hip_atomic_load(&cnt[seg], __ATOMIC_ACQUIRE, __HIP_MEMORY_SCOPE_AGENT);
        float s = 0.f, qq = 0.f;
        const int b0 = sbs[seg], b1 = sbs[seg + 1];
        for (int b = b0; b < b1; ++b) {
            s  += psum[(size_t)b * NFEAT + t];
            qq += psumsq[(size_t)b * NFEAT + t];
        }
        const float cf   = (float)(soff[seg + 1] - soff[seg]);
        const float m    = s / cf;
        const float var  = fmaxf(qq / cf - m * m, 0.f);
        const float rstd = rsqrtf(var + 1e-5f);
        const float sc   = rstd * weight[t];
        scale[(size_t)seg * NFEAT + t] = sc;
        shift[(size_t)seg * NFEAT + t] = bias[t] - m * sc;
    }
}

// ---------------------------------------------------------------------------
// Kernel 2: normalize, chunks in REVERSE order (x tail is L3-hot from the
// stats pass); nt out stores protect that tail while it's consumed.
// ---------------------------------------------------------------------------
__global__ __launch_bounds__(BLK) void k_norm(const float* __restrict__ x,
                                              const int* __restrict__ off,
                                              const int* __restrict__ bs,
                                              int B,
                                              const float* __restrict__ scale,
                                              const float* __restrict__ shift,
                                              float* __restrict__ out) {
    const int t = threadIdx.x;
    __shared__ int soff[132], sbs[132];
    if (t <= B) { soff[t] = off[t]; sbs[t] = bs[t]; }
    __syncthreads();
    const int nch = sbs[B];
    if (blockIdx.x >= nch) return;
    const int c = nch - 1 - blockIdx.x;     // reverse: tail first (L3-hot)

    const int seg = find_seg(sbs, B, c);
    const int r0 = soff[seg] + (c - sbs[seg]) * CH;
    const int r1 = min(r0 + CH, soff[seg + 1]);

    const int rl = t >> 6;
    const int q  = t & 63;

    const float4 sc = reinterpret_cast<const float4*>(scale)[(size_t)seg * NQ + q];
    const float4 sh = reinterpret_cast<const float4*>(shift)[(size_t)seg * NQ + q];

    const float4* x4 = reinterpret_cast<const float4*>(x);
    float4* o4 = reinterpret_cast<float4*>(out);
    int r = r0 + rl;
    #pragma unroll 4
    for (; r + 4 < r1; r += 8) {                    // 2 rows in flight / iter
        const size_t i0 = (size_t)r * NQ + q;
        const size_t i1 = (size_t)(r + 4) * NQ + q;
        float4 v0 = x4[i0];
        float4 v1 = x4[i1];
        float4 o0, o1;
        o0.x = v0.x * sc.x + sh.x;  o0.y = v0.y * sc.y + sh.y;
        o0.z = v0.z * sc.z + sh.z;  o0.w = v0.w * sc.w + sh.w;
        o1.x = v1.x * sc.x + sh.x;  o1.y = v1.y * sc.y + sh.y;
        o1.z = v1.z * sc.z + sh.z;  o1.w = v1.w * sc.w + sh.w;
        nt_store4(&o4[i0], o0);
        nt_store4(&o4[i1], o1);
    }
    if (r < r1) {
        const size_t i0 = (size_t)r * NQ + q;
        float4 v = x4[i0];
        float4 o;
        o.x = v.x * sc.x + sh.x;  o.y = v.y * sc.y + sh.y;
        o.z = v.z * sc.z + sh.z;  o.w = v.w * sc.w + sh.w;
        nt_store4(&o4[i0], o);
    }
}

extern "C" void kernel_launch(void* const* d_in, const int* in_sizes, int n_in,
                              void* d_out, int out_size, void* d_ws, size_t ws_size,
                              hipStream_t stream) {
    const float* x       = (const float*)d_in[0];
    const int*   lengths = (const int*)d_in[1];
    const float* weight  = (const float*)d_in[2];
    const float* bias    = (const float*)d_in[3];
    float*       out     = (float*)d_out;

    const int B = in_sizes[1];               // 128
    const int N = in_sizes[0] / NFEAT;       // 524288
    const int maxCh = N / CH + B;            // chunk upper bound

    // ws layout
    char* ws = (char*)d_ws;
    int*   off    = (int*)ws;                                  // B+1
    int*   bs     = off + 160;                                 // B+1
    int*   cnt    = bs + 160;                                  // B
    float* scale  = (float*)(ws + 4096);                       // B*F
    float* shift  = scale + (size_t)B * NFEAT;                 // B*F
    float* psum   = shift + (size_t)B * NFEAT;                 // maxCh*F
    float* psumsq = psum + (size_t)maxCh * NFEAT;              // maxCh*F

    k_setup<<<1, BLK, 0, stream>>>(lengths, B, off, bs, cnt);
    k_partial<<<maxCh, BLK, 0, stream>>>(x, off, bs, nullptr, B, weight, bias,
                                         psum, psumsq, scale, shift, cnt);
    k_norm<<<maxCh, BLK, 0, stream>>>(x, off, bs, B, scale, shift, out);
}

// Round 9
// 301.886 us; speedup vs baseline: 3.3224x; 1.3442x over previous
//
#include <hip/hip_runtime.h>

#define NFEAT 256
#define NQ    64          // NFEAT/4 float4 quads
#define CH    256         // rows per balanced chunk
#define BLK   256

typedef float f32x4_native __attribute__((ext_vector_type(4)));

__device__ __forceinline__ void nt_store4(float4* p, float4 v) {
    f32x4_native n; n.x = v.x; n.y = v.y; n.z = v.z; n.w = v.w;
    __builtin_nontemporal_store(n, reinterpret_cast<f32x4_native*>(p));
}

// ---------------------------------------------------------------------------
// In-block scan: every block derives off[0..B], bs[0..B] from lengths itself.
// 129-int coalesced load (L2-hot after the first blocks) + 8 LDS scan steps
// ~ <1us, hidden by the other co-resident waves' streaming. This removes the
// separate k_setup launch AND its cross-kernel dependency stall.
// ---------------------------------------------------------------------------
__device__ __forceinline__ void block_scan(const int* __restrict__ lengths, int B,
                                           int* soff, int* sbs) {
    __shared__ int L[BLK], C[BLK];
    const int t = threadIdx.x;
    int len = (t < B) ? lengths[t] : 0;
    L[t] = len;
    C[t] = (len + CH - 1) / CH;
    __syncthreads();
    #pragma unroll
    for (int d = 1; d < BLK; d <<= 1) {
        int a = L[t], c = C[t], aa = 0, cc = 0;
        if (t >= d) { aa = L[t - d]; cc = C[t - d]; }
        __syncthreads();
        L[t] = a + aa; C[t] = c + cc;
        __syncthreads();
    }
    if (t == 0) { soff[0] = 0; sbs[0] = 0; }
    if (t < B)  { soff[t + 1] = L[t]; sbs[t + 1] = C[t]; }
    __syncthreads();
}

// Chunk c -> segment s with sbs[s] <= c < sbs[s+1] (parallel range test).
__device__ __forceinline__ int find_seg(const int* __restrict__ sbs, int B, int c) {
    __shared__ int sseg;
    const int t = threadIdx.x;
    if (t < B && sbs[t] <= c && c < sbs[t + 1]) sseg = t;
    __syncthreads();
    return sseg;
}

// ---------------------------------------------------------------------------
// Kernel 1: per-chunk partial sum / sum-of-squares per feature.
// Regular x loads: we WANT the tail of x resident in L3 for k_norm's
// reversed re-read. Regular psum stores: finalize reads them L2/L3-fast.
// ---------------------------------------------------------------------------
__global__ __launch_bounds__(BLK) void k_partial(const float* __restrict__ x,
                                                 const int* __restrict__ lengths,
                                                 int B,
                                                 float* __restrict__ psum,
                                                 float* __restrict__ psumsq) {
    __shared__ int soff[132], sbs[132];
    block_scan(lengths, B, soff, sbs);

    const int bid = blockIdx.x;
    if (bid >= sbs[B]) return;

    const int seg = find_seg(sbs, B, bid);
    const int r0 = soff[seg] + (bid - sbs[seg]) * CH;
    const int r1 = min(r0 + CH, soff[seg + 1]);

    const int t  = threadIdx.x;
    const int rl = t >> 6;   // 0..3 row lane
    const int q  = t & 63;   // feature quad

    float4 sum = make_float4(0.f, 0.f, 0.f, 0.f);
    float4 sq  = make_float4(0.f, 0.f, 0.f, 0.f);

    const float4* x4 = reinterpret_cast<const float4*>(x);
    #pragma unroll 8
    for (int r = r0 + rl; r < r1; r += 4) {
        float4 v = x4[(size_t)r * NQ + q];
        sum.x += v.x; sum.y += v.y; sum.z += v.z; sum.w += v.w;
        sq.x  += v.x * v.x; sq.y += v.y * v.y; sq.z += v.z * v.z; sq.w += v.w * v.w;
    }

    __shared__ float4 lsum[4][NQ];
    __shared__ float4 lsq[4][NQ];
    lsum[rl][q] = sum;
    lsq[rl][q]  = sq;
    __syncthreads();

    if (rl == 0) {
        float4 a0 = lsum[0][q], a1 = lsum[1][q], a2 = lsum[2][q], a3 = lsum[3][q];
        float4 q0 = lsq[0][q],  q1 = lsq[1][q],  q2 = lsq[2][q],  q3 = lsq[3][q];
        float4 ts, tq;
        ts.x = a0.x + a1.x + a2.x + a3.x;  ts.y = a0.y + a1.y + a2.y + a3.y;
        ts.z = a0.z + a1.z + a2.z + a3.z;  ts.w = a0.w + a1.w + a2.w + a3.w;
        tq.x = q0.x + q1.x + q2.x + q3.x;  tq.y = q0.y + q1.y + q2.y + q3.y;
        tq.z = q0.z + q1.z + q2.z + q3.z;  tq.w = q0.w + q1.w + q2.w + q3.w;
        reinterpret_cast<float4*>(psum)[(size_t)bid * NQ + q]   = ts;
        reinterpret_cast<float4*>(psumsq)[(size_t)bid * NQ + q] = tq;
    }
}

// ---------------------------------------------------------------------------
// Kernel 2: reduce each segment's contiguous chunk range -> scale/shift.
// 4 independent accumulator pairs => 8 loads in flight (was a 2-load
// dependent chain over up to ~87 iterations => latency-bound tail).
// ---------------------------------------------------------------------------
__global__ __launch_bounds__(BLK) void k_finalize(const float* __restrict__ psum,
                                                  const float* __restrict__ psumsq,
                                                  const int* __restrict__ lengths,
                                                  int B,
                                                  const float* __restrict__ weight,
                                                  const float* __restrict__ bias,
                                                  float* __restrict__ scale,
                                                  float* __restrict__ shift) {
    __shared__ int soff[132], sbs[132];
    block_scan(lengths, B, soff, sbs);

    const int seg = blockIdx.x;
    const int f   = threadIdx.x;
    const int b0 = sbs[seg], b1 = sbs[seg + 1];

    float s0 = 0.f, s1 = 0.f, s2 = 0.f, s3 = 0.f;
    float q0 = 0.f, q1 = 0.f, q2 = 0.f, q3 = 0.f;
    int b = b0;
    for (; b + 3 < b1; b += 4) {
        s0 += psum[(size_t)(b + 0) * NFEAT + f];  q0 += psumsq[(size_t)(b + 0) * NFEAT + f];
        s1 += psum[(size_t)(b + 1) * NFEAT + f];  q1 += psumsq[(size_t)(b + 1) * NFEAT + f];
        s2 += psum[(size_t)(b + 2) * NFEAT + f];  q2 += psumsq[(size_t)(b + 2) * NFEAT + f];
        s3 += psum[(size_t)(b + 3) * NFEAT + f];  q3 += psumsq[(size_t)(b + 3) * NFEAT + f];
    }
    for (; b < b1; ++b) {
        s0 += psum[(size_t)b * NFEAT + f];
        q0 += psumsq[(size_t)b * NFEAT + f];
    }
    const float s  = (s0 + s1) + (s2 + s3);
    const float qq = (q0 + q1) + (q2 + q3);

    const float cnt  = (float)(soff[seg + 1] - soff[seg]);
    const float m    = s / cnt;
    const float var  = fmaxf(qq / cnt - m * m, 0.f);
    const float rstd = rsqrtf(var + 1e-5f);
    const float sc   = rstd * weight[f];
    scale[(size_t)seg * NFEAT + f] = sc;
    shift[(size_t)seg * NFEAT + f] = bias[f] - m * sc;
}

// ---------------------------------------------------------------------------
// Kernel 3: normalize, chunks in REVERSE order (x tail is L3-hot from the
// stats pass); nt out stores protect that tail while it's consumed.
// ---------------------------------------------------------------------------
__global__ __launch_bounds__(BLK) void k_norm(const float* __restrict__ x,
                                              const int* __restrict__ lengths,
                                              int B,
                                              const float* __restrict__ scale,
                                              const float* __restrict__ shift,
                                              float* __restrict__ out) {
    __shared__ int soff[132], sbs[132];
    block_scan(lengths, B, soff, sbs);

    const int nch = sbs[B];
    if ((int)blockIdx.x >= nch) return;
    const int c = nch - 1 - blockIdx.x;     // reverse: tail first (L3-hot)

    const int seg = find_seg(sbs, B, c);
    const int r0 = soff[seg] + (c - sbs[seg]) * CH;
    const int r1 = min(r0 + CH, soff[seg + 1]);

    const int t  = threadIdx.x;
    const int rl = t >> 6;
    const int q  = t & 63;

    const float4 sc = reinterpret_cast<const float4*>(scale)[(size_t)seg * NQ + q];
    const float4 sh = reinterpret_cast<const float4*>(shift)[(size_t)seg * NQ + q];

    const float4* x4 = reinterpret_cast<const float4*>(x);
    float4* o4 = reinterpret_cast<float4*>(out);
    #pragma unroll 8
    for (int r = r0 + rl; r < r1; r += 4) {
        const size_t idx = (size_t)r * NQ + q;
        float4 v = x4[idx];
        float4 o;
        o.x = v.x * sc.x + sh.x;
        o.y = v.y * sc.y + sh.y;
        o.z = v.z * sc.z + sh.z;
        o.w = v.w * sc.w + sh.w;
        nt_store4(&o4[idx], o);
    }
}

extern "C" void kernel_launch(void* const* d_in, const int* in_sizes, int n_in,
                              void* d_out, int out_size, void* d_ws, size_t ws_size,
                              hipStream_t stream) {
    const float* x       = (const float*)d_in[0];
    const int*   lengths = (const int*)d_in[1];
    const float* weight  = (const float*)d_in[2];
    const float* bias    = (const float*)d_in[3];
    float*       out     = (float*)d_out;

    const int B = in_sizes[1];               // 128
    const int N = in_sizes[0] / NFEAT;       // 524288
    const int maxCh = N / CH + B;            // chunk upper bound

    // ws layout
    char* ws = (char*)d_ws;
    float* scale  = (float*)(ws + 4096);                       // B*F
    float* shift  = scale + (size_t)B * NFEAT;                 // B*F
    float* psum   = shift + (size_t)B * NFEAT;                 // maxCh*F
    float* psumsq = psum + (size_t)maxCh * NFEAT;              // maxCh*F

    k_partial<<<maxCh, BLK, 0, stream>>>(x, lengths, B, psum, psumsq);
    k_finalize<<<B, BLK, 0, stream>>>(psum, psumsq, lengths, B, weight, bias, scale, shift);
    k_norm<<<maxCh, BLK, 0, stream>>>(x, lengths, B, scale, shift, out);
}